// Round 23
// baseline (103.709 us; speedup 1.0000x reference)
//
#include <hip/hip_runtime.h>
#include <math.h>

// PoseMLP, transposed split-f16 MFMA, R23: R14-final + PACKED-F32 epilogues.
// R22 reproduced R14 at 93.5us (MfmaUtil 35%, VALUBusy 58%, no pipe
// saturated -> latency plateau at 2 waves/SIMD). Last lever: the epilogue
// math acts on ADJACENT acc register pairs (2m,2m+1) -> express as
// float ext_vector(2) elementwise fma/max/sub/mul so the backend emits
// VOP3P v_pk_fma_f32 / v_pk_max_f32 / v_pk_mul_f32 (gfx90a+): ~150-200
// fewer VALU instrs/iter (~15%), IEEE-identical per element, zero register
// footprint change. If pk-ops don't form: neutral.
//
// Math: a = hi + lo*2^-12 (hi=RTZ_f16(a), lo=RTZ_f16((a-hi)*4096));
//   res = acc_hh + (acc_hl + acc_lh)*2^-12; lo*lo dropped (~2^-24).
//   L1 bias in k=7 slot (B k7 = 1.0 g0 lanes, A k7 = split(b1)).
// v_mfma_f32_32x32x16_f16 layouts (verified R5..R22):
//   A: row=lane&31, k=8*(lane>>5)+j ; B: col=lane&31, k=8*(lane>>5)+j
//   D: col=lane&31, row=(i&3)+8*(i>>2)+4*(lane>>5)
// sigma relabeling: packed D word (ct,m) == B-frag kb=2ct+(m>>2), w=m&3;
// consumer weight columns pre-permuted by sigma_inv at LDS-stage time.

typedef _Float16 half8  __attribute__((ext_vector_type(8)));
typedef __fp16   fp16x2 __attribute__((ext_vector_type(2)));
typedef float    floatx16 __attribute__((ext_vector_type(16)));
typedef float    f32x2 __attribute__((ext_vector_type(2)));
typedef unsigned int uint2v __attribute__((ext_vector_type(2)));

#define MFMA32(a, b, c) __builtin_amdgcn_mfma_f32_32x32x16_f16((a), (b), (c), 0, 0, 0)
#define LO_SCALE 2.44140625e-4f  /* 2^-12 */

union PairU { fp16x2 h; unsigned int u; };
union FragU { unsigned int w[4]; half8 h; };

// scalar split (cold path: weight staging)
static __device__ inline void split_pack2(float v0, float v1,
                                          unsigned int& hw, unsigned int& lw) {
    PairU hp, lp;
    hp.h = __builtin_amdgcn_cvt_pkrtz(v0, v1);          // 1 instr, RTZ
    float f0 = (float)hp.h[0], f1 = (float)hp.h[1];
    lp.h = __builtin_amdgcn_cvt_pkrtz((v0 - f0) * 4096.0f,
                                      (v1 - f1) * 4096.0f);
    hw = hp.u; lw = lp.u;
}

// packed split (hot path): (v - hi)*4096 as v_pk ops
static __device__ inline void split_pack2p(f32x2 v,
                                           unsigned int& hw, unsigned int& lw) {
    PairU hp, lp;
    hp.h = __builtin_amdgcn_cvt_pkrtz(v[0], v[1]);
    f32x2 f; f[0] = (float)hp.h[0]; f[1] = (float)hp.h[1];
    f32x2 r = (v - f) * 4096.0f;                        // pk_add + pk_mul
    lp.h = __builtin_amdgcn_cvt_pkrtz(r[0], r[1]);
    hw = hp.u; lw = lp.u;
}

// B k-slot -> producer's natural output-neuron position.
static __device__ inline int sigma_inv(int k) {
    int ci = k >> 5, r = k & 31;
    int m  = 4 * ((r >> 4) & 1) + ((r >> 1) & 3);
    int i  = 2 * m + (r & 1);
    int gD = (r >> 3) & 1;
    return 32 * ci + (i & 3) + 8 * (i >> 2) + 4 * gD;
}

// 2x2 half-block transpose (quat epilogue only)
static __device__ inline void swap32(unsigned int a, unsigned int b,
                                     unsigned int& lo, unsigned int& hi) {
    uint2v r = __builtin_amdgcn_permlane32_swap(a, b, false, false);
    lo = r[0]; hi = r[1];
}

__global__ __launch_bounds__(256, 2) void pose_mlp_mfma_k(
    const float* __restrict__ x,
    const float* __restrict__ W1, const float* __restrict__ b1,
    const float* __restrict__ W2, const float* __restrict__ b2,
    const float* __restrict__ W3, const float* __restrict__ b3,
    float* __restrict__ out, int nrows)
{
    const int tid  = threadIdx.x;
    const int lane = tid & 63;
    const int wv   = tid >> 6;
    const int g    = lane >> 5;   // lane half (k-group / row-group)
    const int n5   = lane & 31;   // neuron row (A) / batch col (B/D)

    __shared__ half8 ldsW[28 * 64];   // 28 KB of pre-split weight fragments

    // ---- stage weight fragments (4 waves cooperatively, own lane each) ----
    for (int p = wv; p < 14; p += 4) {
        FragU H, L;
        if (p < 2) {                       // W1 pair, ct = p
            const int ct = p;
#pragma unroll
            for (int m = 0; m < 4; ++m) {
                int k0 = 2 * m, k1 = 2 * m + 1;
                float a0 = (g == 0) ? W1[(ct * 32 + n5) * 7 + k0] : 0.0f;
                float a1 = (g == 0) ? ((k1 < 7) ? W1[(ct * 32 + n5) * 7 + k1]
                                                : b1[ct * 32 + n5]) : 0.0f;
                split_pack2(a0, a1, H.w[m], L.w[m]);
            }
        } else if (p < 10) {               // W2 pair, q = p-2 -> (ct, kb)
            const int q = p - 2, ct = q >> 2, kb = q & 3;
            const float* wrow = W2 + (ct * 32 + n5) * 64;
#pragma unroll
            for (int m = 0; m < 4; ++m) {
                int k0 = kb * 16 + g * 8 + 2 * m;
                split_pack2(wrow[sigma_inv(k0)], wrow[sigma_inv(k0 + 1)],
                            H.w[m], L.w[m]);
            }
        } else {                           // W3 pair, kb = p-10
            const int kb = p - 10;
            const bool nv = (n5 < 7);
#pragma unroll
            for (int m = 0; m < 4; ++m) {
                int k0 = kb * 16 + g * 8 + 2 * m;
                float a0 = nv ? W3[n5 * 64 + sigma_inv(k0)]     : 0.0f;
                float a1 = nv ? W3[n5 * 64 + sigma_inv(k0 + 1)] : 0.0f;
                split_pack2(a0, a1, H.w[m], L.w[m]);
            }
        }
        ldsW[p * 64 + lane]        = H.h;
        ldsW[(14 + p) * 64 + lane] = L.h;
    }

    // loop-invariant accumulator C operands
    floatx16 zero16;
#pragma unroll
    for (int i = 0; i < 16; ++i) zero16[i] = 0.0f;
    floatx16 bias2v[2];
#pragma unroll
    for (int ct = 0; ct < 2; ++ct)
#pragma unroll
        for (int i = 0; i < 16; ++i)
            bias2v[ct][i] = b2[ct * 32 + (i & 3) + 8 * (i >> 2) + 4 * g];
    float b3t[4];
#pragma unroll
    for (int i = 0; i < 4; ++i)
        b3t[i] = g ? ((i < 3) ? b3[4 + i] : 0.0f) : b3[i];
    const float x7 = (g == 0) ? 1.0f : 0.0f;
    const f32x2 los = { LO_SCALE, LO_SCALE };
    const f32x2 zz  = { 0.0f, 0.0f };

    __syncthreads();   // weights visible to all waves

    // ---------------- main loop: ITERS x 128 rows/block ----------------
    const int ITERS = 16;
    const int blk0 = blockIdx.x * (ITERS * 128);

    float xv[7] = {0.f,0.f,0.f,0.f,0.f,0.f,0.f};  // stays 0 in g1 lanes
    {
        int r = blk0 + wv * 32 + n5;
        if (g == 0 && r < nrows) {
            const float* xr = x + (size_t)r * 7;
#pragma unroll
            for (int j = 0; j < 7; ++j) xv[j] = xr[j];
        }
    }

    for (int it = 0; it < ITERS; ++it) {
        const int r0 = blk0 + it * 128 + wv * 32;

        // ---- X B-frag (packed splits) ----
        FragU xH, xL;
        { f32x2 v; v[0]=xv[0]; v[1]=xv[1]; split_pack2p(v, xH.w[0], xL.w[0]); }
        { f32x2 v; v[0]=xv[2]; v[1]=xv[3]; split_pack2p(v, xH.w[1], xL.w[1]); }
        { f32x2 v; v[0]=xv[4]; v[1]=xv[5]; split_pack2p(v, xH.w[2], xL.w[2]); }
        { f32x2 v; v[0]=xv[6]; v[1]=x7;    split_pack2p(v, xH.w[3], xL.w[3]); }

        if (it < ITERS - 1) {
            int r = r0 + 128 + n5;
            if (g == 0 && r < nrows) {
                const float* xr = x + (size_t)r * 7;
#pragma unroll
                for (int j = 0; j < 7; ++j) xv[j] = xr[j];
            }
        }

        // ---- Layer 1: h1^T ; packed epilogue -> L2 B-frags (sigma) ----
        FragU AH[4], AL[4];
#pragma unroll
        for (int ct = 0; ct < 2; ++ct) {
            half8 wh = ldsW[ct * 64 + lane];
            half8 wl = ldsW[(14 + ct) * 64 + lane];
            floatx16 ah = MFMA32(wh, xH.h, zero16);
            floatx16 al = MFMA32(wh, xL.h, zero16);
            al = MFMA32(wl, xH.h, al);
#pragma unroll
            for (int m = 0; m < 8; ++m) {
                f32x2 av; av[0] = al[2*m]; av[1] = al[2*m+1];
                f32x2 hv; hv[0] = ah[2*m]; hv[1] = ah[2*m+1];
                f32x2 v = __builtin_elementwise_fma(av, los, hv);  // pk_fma
                v = __builtin_elementwise_max(v, zz);              // pk_max
                const int kb = 2 * ct + (m >> 2), w = m & 3;
                split_pack2p(v, AH[kb].w[w], AL[kb].w[w]);
            }
        }

        // ---- Layer 2: h2^T ; packed epilogue -> L3 B-frags (sigma) ----
        FragU BH[4], BL[4];
#pragma unroll
        for (int ct = 0; ct < 2; ++ct) {
            floatx16 ch, cl;
#pragma unroll
            for (int kb = 0; kb < 4; ++kb) {
                half8 wh = ldsW[(2 + ct * 4 + kb) * 64 + lane];
                half8 wl = ldsW[(16 + ct * 4 + kb) * 64 + lane];
                if (kb == 0) {
                    ch = MFMA32(wh, AH[0].h, bias2v[ct]);
                    cl = MFMA32(wh, AL[0].h, zero16);
                    cl = MFMA32(wl, AH[0].h, cl);
                } else {
                    ch = MFMA32(wh, AH[kb].h, ch);
                    cl = MFMA32(wh, AL[kb].h, cl);
                    cl = MFMA32(wl, AH[kb].h, cl);
                }
            }
#pragma unroll
            for (int m = 0; m < 8; ++m) {
                f32x2 av; av[0] = cl[2*m]; av[1] = cl[2*m+1];
                f32x2 hv; hv[0] = ch[2*m]; hv[1] = ch[2*m+1];
                f32x2 v = __builtin_elementwise_fma(av, los, hv);
                v = __builtin_elementwise_max(v, zz);
                const int kb = 2 * ct + (m >> 2), w = m & 3;
                split_pack2p(v, BH[kb].w[w], BL[kb].w[w]);
            }
        }

        // ---- Layer 3: o^T rows 0..6 + quat epilogue ----
        {
            floatx16 oh, ol;
#pragma unroll
            for (int kb = 0; kb < 4; ++kb) {
                half8 wh = ldsW[(10 + kb) * 64 + lane];
                half8 wl = ldsW[(24 + kb) * 64 + lane];
                if (kb == 0) {
                    oh = MFMA32(wh, BH[0].h, zero16);
                    ol = MFMA32(wh, BL[0].h, zero16);
                    ol = MFMA32(wl, BH[0].h, ol);
                } else {
                    oh = MFMA32(wh, BH[kb].h, oh);
                    ol = MFMA32(wh, BL[kb].h, ol);
                    ol = MFMA32(wl, BH[kb].h, ol);
                }
            }
            float c0 = fmaf(ol[0], LO_SCALE, oh[0]) + b3t[0];
            float c1 = fmaf(ol[1], LO_SCALE, oh[1]) + b3t[1];
            float c2 = fmaf(ol[2], LO_SCALE, oh[2]) + b3t[2];
            float c3 = fmaf(ol[3], LO_SCALE, oh[3]) + b3t[3];

            float p = g ? fmaf(c2, c2, fmaf(c1, c1, c0 * c0)) : c3 * c3;
            unsigned int plo, phi;
            swap32(__float_as_uint(p), __float_as_uint(p), plo, phi);
            float other = __uint_as_float(g ? plo : phi);
            float s = p + other;
            float rn = 1.0f / sqrtf(s);

            int r = r0 + n5;
            if (r < nrows) {
                float* orow = out + (size_t)r * 7;
                if (g == 0) {
                    orow[0] = c0; orow[1] = c1; orow[2] = c2; orow[3] = c3 * rn;
                } else {
                    orow[4] = c0 * rn; orow[5] = c1 * rn; orow[6] = c2 * rn;
                }
            }
        }
    }
}

extern "C" void kernel_launch(void* const* d_in, const int* in_sizes, int n_in,
                              void* d_out, int out_size, void* d_ws, size_t ws_size,
                              hipStream_t stream)
{
    const float* x  = (const float*)d_in[0];
    const float* W1 = (const float*)d_in[1];
    const float* b1 = (const float*)d_in[2];
    const float* W2 = (const float*)d_in[3];
    const float* b2 = (const float*)d_in[4];
    const float* W3 = (const float*)d_in[5];
    const float* b3 = (const float*)d_in[6];
    float* out = (float*)d_out;

    const int nrows = in_sizes[0] / 7;
    const int rows_per_block = 16 * 128;  // ITERS * 128
    const int grid = (nrows + rows_per_block - 1) / rows_per_block;
    pose_mlp_mfma_k<<<grid, 256, 0, stream>>>(x, W1, b1, W2, b2, W3, b3, out, nrows);
}

// Round 24
// 93.586 us; speedup vs baseline: 1.1082x; 1.1082x over previous
//
#include <hip/hip_runtime.h>
#include <math.h>

// PoseMLP, transposed split-f16 MFMA — FINAL (R14 structure, best measured:
// 93.5-94.0 us across two independent runs; absmax 0.0039; 3.3x over the
// 307us fp32-VALU baseline).
//
// Closed-out optimization ledger (all measured on MI355X):
//   307us  fp32 1-thread/row (VALUBusy 79%)          [R2]
//   181us  split-f16 MFMA, LDS transposes            [R5]
//   115us  register-resident transposed (+shfl_xor)  [R7]
//   101us  permlane32_swap exchanges                 [R9]
//   102us  sigma-permute (zero-instr transitions)    [R10, neutral]
//    94us  weights -> LDS (28KB, kills accvgpr churn)[R14]  << FINAL
//   Failed levers (all measured): 1-wave blocks -34% [R12]; chain-split
//   spills [R13/R16]; launch_bounds(256,3) VGPR=84 -> 548MB scratch -174%
//   [R15]; W2-H reg hoist -3% [R21]; packed-f32 epilogue -11% with
//   VALUBusy 58->42% [R23] -- proving VALU work was latency FILLER, not
//   the bound. Wall = dependency latency at 2 waves/SIMD, pinned by ~250
//   unified VGPR+AGPR demand. No pipe saturated (VALU 58%, LDS 22%,
//   HBM 10%, MFMA-issue <10%); breaking it needs a structurally smaller
//   register footprint than this design admits.
//
// Math: a = hi + lo*2^-12 (hi=RTZ_f16(a), lo=RTZ_f16((a-hi)*4096));
//   res = acc_hh + (acc_hl + acc_lh)*2^-12; lo*lo dropped (~2^-24) ->
//   fp32-class error (absmax equals the fp32 baseline's 0.0039).
//   L1 bias in k=7 slot (B k7 = 1.0 g0 lanes, A k7 = split(b1)).
// v_mfma_f32_32x32x16_f16 layouts (verified R5..R23):
//   A: row=lane&31, k=8*(lane>>5)+j ; B: col=lane&31, k=8*(lane>>5)+j
//   D: col=lane&31, row=(i&3)+8*(i>>2)+4*(lane>>5)
// sigma relabeling: packed D word (ct,m) == B-frag kb=2ct+(m>>2), w=m&3;
// consumer weight columns pre-permuted by sigma_inv at LDS-stage time ->
// zero-instruction layer transitions.

typedef _Float16 half8  __attribute__((ext_vector_type(8)));
typedef __fp16   fp16x2 __attribute__((ext_vector_type(2)));
typedef float    floatx16 __attribute__((ext_vector_type(16)));
typedef unsigned int uint2v __attribute__((ext_vector_type(2)));

#define MFMA32(a, b, c) __builtin_amdgcn_mfma_f32_32x32x16_f16((a), (b), (c), 0, 0, 0)
#define LO_SCALE 2.44140625e-4f  /* 2^-12 */

union PairU { fp16x2 h; unsigned int u; };
union FragU { unsigned int w[4]; half8 h; };

static __device__ inline void split_pack2(float v0, float v1,
                                          unsigned int& hw, unsigned int& lw) {
    PairU hp, lp;
    hp.h = __builtin_amdgcn_cvt_pkrtz(v0, v1);          // 1 instr, RTZ
    float f0 = (float)hp.h[0], f1 = (float)hp.h[1];
    lp.h = __builtin_amdgcn_cvt_pkrtz((v0 - f0) * 4096.0f,
                                      (v1 - f1) * 4096.0f);
    hw = hp.u; lw = lp.u;
}

// B k-slot -> producer's natural output-neuron position.
static __device__ inline int sigma_inv(int k) {
    int ci = k >> 5, r = k & 31;
    int m  = 4 * ((r >> 4) & 1) + ((r >> 1) & 3);
    int i  = 2 * m + (r & 1);
    int gD = (r >> 3) & 1;
    return 32 * ci + (i & 3) + 8 * (i >> 2) + 4 * gD;
}

// 2x2 half-block transpose (quat epilogue only)
static __device__ inline void swap32(unsigned int a, unsigned int b,
                                     unsigned int& lo, unsigned int& hi) {
    uint2v r = __builtin_amdgcn_permlane32_swap(a, b, false, false);
    lo = r[0]; hi = r[1];
}

__global__ __launch_bounds__(256, 2) void pose_mlp_mfma_l(
    const float* __restrict__ x,
    const float* __restrict__ W1, const float* __restrict__ b1,
    const float* __restrict__ W2, const float* __restrict__ b2,
    const float* __restrict__ W3, const float* __restrict__ b3,
    float* __restrict__ out, int nrows)
{
    const int tid  = threadIdx.x;
    const int lane = tid & 63;
    const int wv   = tid >> 6;
    const int g    = lane >> 5;   // lane half (k-group / row-group)
    const int n5   = lane & 31;   // neuron row (A) / batch col (B/D)

    __shared__ half8 ldsW[28 * 64];   // 28 KB of pre-split weight fragments

    // ---- stage weight fragments (4 waves cooperatively, own lane each) ----
    for (int p = wv; p < 14; p += 4) {
        FragU H, L;
        if (p < 2) {                       // W1 pair, ct = p
            const int ct = p;
#pragma unroll
            for (int m = 0; m < 4; ++m) {
                int k0 = 2 * m, k1 = 2 * m + 1;
                float a0 = (g == 0) ? W1[(ct * 32 + n5) * 7 + k0] : 0.0f;
                float a1 = (g == 0) ? ((k1 < 7) ? W1[(ct * 32 + n5) * 7 + k1]
                                                : b1[ct * 32 + n5]) : 0.0f;
                split_pack2(a0, a1, H.w[m], L.w[m]);
            }
        } else if (p < 10) {               // W2 pair, q = p-2 -> (ct, kb)
            const int q = p - 2, ct = q >> 2, kb = q & 3;
            const float* wrow = W2 + (ct * 32 + n5) * 64;
#pragma unroll
            for (int m = 0; m < 4; ++m) {
                int k0 = kb * 16 + g * 8 + 2 * m;
                split_pack2(wrow[sigma_inv(k0)], wrow[sigma_inv(k0 + 1)],
                            H.w[m], L.w[m]);
            }
        } else {                           // W3 pair, kb = p-10
            const int kb = p - 10;
            const bool nv = (n5 < 7);
#pragma unroll
            for (int m = 0; m < 4; ++m) {
                int k0 = kb * 16 + g * 8 + 2 * m;
                float a0 = nv ? W3[n5 * 64 + sigma_inv(k0)]     : 0.0f;
                float a1 = nv ? W3[n5 * 64 + sigma_inv(k0 + 1)] : 0.0f;
                split_pack2(a0, a1, H.w[m], L.w[m]);
            }
        }
        ldsW[p * 64 + lane]        = H.h;
        ldsW[(14 + p) * 64 + lane] = L.h;
    }

    // loop-invariant accumulator C operands
    floatx16 zero16;
#pragma unroll
    for (int i = 0; i < 16; ++i) zero16[i] = 0.0f;
    floatx16 bias2v[2];
#pragma unroll
    for (int ct = 0; ct < 2; ++ct)
#pragma unroll
        for (int i = 0; i < 16; ++i)
            bias2v[ct][i] = b2[ct * 32 + (i & 3) + 8 * (i >> 2) + 4 * g];
    float b3t[4];
#pragma unroll
    for (int i = 0; i < 4; ++i)
        b3t[i] = g ? ((i < 3) ? b3[4 + i] : 0.0f) : b3[i];
    const float x7 = (g == 0) ? 1.0f : 0.0f;

    __syncthreads();   // weights visible to all waves

    // ---------------- main loop: ITERS x 128 rows/block ----------------
    const int ITERS = 16;
    const int blk0 = blockIdx.x * (ITERS * 128);

    float xv[7] = {0.f,0.f,0.f,0.f,0.f,0.f,0.f};  // stays 0 in g1 lanes
    {
        int r = blk0 + wv * 32 + n5;
        if (g == 0 && r < nrows) {
            const float* xr = x + (size_t)r * 7;
#pragma unroll
            for (int j = 0; j < 7; ++j) xv[j] = xr[j];
        }
    }

    for (int it = 0; it < ITERS; ++it) {
        const int r0 = blk0 + it * 128 + wv * 32;

        // ---- X B-frag ----
        FragU xH, xL;
        split_pack2(xv[0], xv[1], xH.w[0], xL.w[0]);
        split_pack2(xv[2], xv[3], xH.w[1], xL.w[1]);
        split_pack2(xv[4], xv[5], xH.w[2], xL.w[2]);
        split_pack2(xv[6], x7,    xH.w[3], xL.w[3]);

        if (it < ITERS - 1) {
            int r = r0 + 128 + n5;
            if (g == 0 && r < nrows) {
                const float* xr = x + (size_t)r * 7;
#pragma unroll
                for (int j = 0; j < 7; ++j) xv[j] = xr[j];
            }
        }

        // ---- Layer 1: h1^T ; pack DIRECTLY into L2 B-frags (sigma) ----
        FragU AH[4], AL[4];
#pragma unroll
        for (int ct = 0; ct < 2; ++ct) {
            half8 wh = ldsW[ct * 64 + lane];
            half8 wl = ldsW[(14 + ct) * 64 + lane];
            floatx16 ah = MFMA32(wh, xH.h, zero16);
            floatx16 al = MFMA32(wh, xL.h, zero16);
            al = MFMA32(wl, xH.h, al);
#pragma unroll
            for (int m = 0; m < 8; ++m) {
                float v0 = fmaxf(fmaf(al[2*m],   LO_SCALE, ah[2*m]),   0.0f);
                float v1 = fmaxf(fmaf(al[2*m+1], LO_SCALE, ah[2*m+1]), 0.0f);
                const int kb = 2 * ct + (m >> 2), w = m & 3;
                split_pack2(v0, v1, AH[kb].w[w], AL[kb].w[w]);
            }
        }

        // ---- Layer 2: h2^T ; pack into L3 B-frags (sigma) ----
        FragU BH[4], BL[4];
#pragma unroll
        for (int ct = 0; ct < 2; ++ct) {
            floatx16 ch, cl;
#pragma unroll
            for (int kb = 0; kb < 4; ++kb) {
                half8 wh = ldsW[(2 + ct * 4 + kb) * 64 + lane];
                half8 wl = ldsW[(16 + ct * 4 + kb) * 64 + lane];
                if (kb == 0) {
                    ch = MFMA32(wh, AH[0].h, bias2v[ct]);
                    cl = MFMA32(wh, AL[0].h, zero16);
                    cl = MFMA32(wl, AH[0].h, cl);
                } else {
                    ch = MFMA32(wh, AH[kb].h, ch);
                    cl = MFMA32(wh, AL[kb].h, cl);
                    cl = MFMA32(wl, AH[kb].h, cl);
                }
            }
#pragma unroll
            for (int m = 0; m < 8; ++m) {
                float v0 = fmaxf(fmaf(cl[2*m],   LO_SCALE, ch[2*m]),   0.0f);
                float v1 = fmaxf(fmaf(cl[2*m+1], LO_SCALE, ch[2*m+1]), 0.0f);
                const int kb = 2 * ct + (m >> 2), w = m & 3;
                split_pack2(v0, v1, BH[kb].w[w], BL[kb].w[w]);
            }
        }

        // ---- Layer 3: o^T rows 0..6 + quat epilogue ----
        {
            floatx16 oh, ol;
#pragma unroll
            for (int kb = 0; kb < 4; ++kb) {
                half8 wh = ldsW[(10 + kb) * 64 + lane];
                half8 wl = ldsW[(24 + kb) * 64 + lane];
                if (kb == 0) {
                    oh = MFMA32(wh, BH[0].h, zero16);
                    ol = MFMA32(wh, BL[0].h, zero16);
                    ol = MFMA32(wl, BH[0].h, ol);
                } else {
                    oh = MFMA32(wh, BH[kb].h, oh);
                    ol = MFMA32(wh, BL[kb].h, ol);
                    ol = MFMA32(wl, BH[kb].h, ol);
                }
            }
            float c0 = fmaf(ol[0], LO_SCALE, oh[0]) + b3t[0];
            float c1 = fmaf(ol[1], LO_SCALE, oh[1]) + b3t[1];
            float c2 = fmaf(ol[2], LO_SCALE, oh[2]) + b3t[2];
            float c3 = fmaf(ol[3], LO_SCALE, oh[3]) + b3t[3];

            float p = g ? fmaf(c2, c2, fmaf(c1, c1, c0 * c0)) : c3 * c3;
            unsigned int plo, phi;
            swap32(__float_as_uint(p), __float_as_uint(p), plo, phi);
            float other = __uint_as_float(g ? plo : phi);
            float s = p + other;
            float rn = 1.0f / sqrtf(s);

            int r = r0 + n5;
            if (r < nrows) {
                float* orow = out + (size_t)r * 7;
                if (g == 0) {
                    orow[0] = c0; orow[1] = c1; orow[2] = c2; orow[3] = c3 * rn;
                } else {
                    orow[4] = c0 * rn; orow[5] = c1 * rn; orow[6] = c2 * rn;
                }
            }
        }
    }
}

extern "C" void kernel_launch(void* const* d_in, const int* in_sizes, int n_in,
                              void* d_out, int out_size, void* d_ws, size_t ws_size,
                              hipStream_t stream)
{
    const float* x  = (const float*)d_in[0];
    const float* W1 = (const float*)d_in[1];
    const float* b1 = (const float*)d_in[2];
    const float* W2 = (const float*)d_in[3];
    const float* b2 = (const float*)d_in[4];
    const float* W3 = (const float*)d_in[5];
    const float* b3 = (const float*)d_in[6];
    float* out = (float*)d_out;

    const int nrows = in_sizes[0] / 7;
    const int rows_per_block = 16 * 128;  // ITERS * 128
    const int grid = (nrows + rows_per_block - 1) / rows_per_block;
    pose_mlp_mfma_l<<<grid, 256, 0, stream>>>(x, W1, b1, W2, b2, W3, b3, out, nrows);
}